// Round 3
// baseline (21309.082 us; speedup 1.0000x reference)
//
#include <hip/hip_runtime.h>

#define DIMR   1024
#define BSZ    64
#define TSTEPS 512
#define INDIM  300
#define LEAKF  0.5f

#define GROUPS 16   // batch groups
#define WPG    16   // workgroups per group
#define BPG    4    // batches per group
#define WGSZ   512  // threads per workgroup
#define BAR_STRIDE 64  // uints between group counters (256B)

// ---------------------------------------------------------------------------
// Kernel 1: compute lengths[b] into the tail of d_out (as float), and zero the
// group-barrier counters in d_ws (ws is re-poisoned 0xAA before every launch).
// ---------------------------------------------------------------------------
__global__ void lengths_init_kernel(const float* __restrict__ emb,
                                    float* __restrict__ out,
                                    unsigned* __restrict__ barriers) {
  const int b   = blockIdx.x;
  const int tid = threadIdx.x;
  if (b == 0) {
    for (int i = tid; i < GROUPS * BAR_STRIDE; i += 256) barriers[i] = 0u;
  }
  const int wave = tid >> 6, lane = tid & 63;
  int cnt = 0;
  for (int t = wave; t < TSTEPS; t += 4) {
    const float* row = emb + ((size_t)t * BSZ + b) * INDIM;
    float s = 0.f;
    for (int i = lane; i < INDIM; i += 64) s += row[i];
#pragma unroll
    for (int m = 32; m >= 1; m >>= 1) s += __shfl_xor(s, m, 64);
    if (s != 0.f) ++cnt;
  }
  __shared__ int part[4];
  if (lane == 0) part[wave] = cnt;
  __syncthreads();
  if (tid == 0)
    out[(size_t)BSZ * TSTEPS * DIMR + b] =
        (float)(part[0] + part[1] + part[2] + part[3]);
}

// ---------------------------------------------------------------------------
// Kernel 2: persistent recurrent kernel.
// Grid: 256 wgs x 512 thr. Group g (16 wgs, one XCD) owns batches [4g,4g+4).
// wg slice s owns rows [64s, 64s+64) of layer_w, held in registers
// (lane: row d = 64s + 8*wave + (lane>>3), cols [128c,128c+128), c=lane&7).
// Per step: dot + shfl-reduce over the 8 chunk lanes -> tanh/leak/mask ->
// store to d_out (which doubles as the x exchange buffer) -> group barrier
// (device-scope atomic) -> reload full x slice for the 4 batches into LDS.
// ---------------------------------------------------------------------------
__global__ __launch_bounds__(WGSZ, 2) void esn_recurrent_kernel(
    const float* __restrict__ emb,
    const float* __restrict__ inw,
    const float* __restrict__ lw,
    const float* __restrict__ bias,
    const float* __restrict__ x0,
    float* __restrict__ out,
    unsigned* __restrict__ barriers) {

  __shared__ float xbuf[BPG][DIMR];     // current state, XOR-swizzled
  __shared__ float ebuf[2][BPG][320];   // emb tiles, padded 300->320 (pads=0)

  const int bid = blockIdx.x;
  const int xcd = bid & 7;
  const int ix  = bid >> 3;               // 0..31
  const int group = xcd * 2 + (ix & 1);   // 0..15  (16 wgs of a group share an XCD)
  const int slice = ix >> 1;              // 0..15
  const int tid  = threadIdx.x;
  const int w    = tid >> 6;
  const int lane = tid & 63;
  const int rl   = lane >> 3;
  const int c    = lane & 7;
  const int d    = slice * 64 + w * 8 + rl;
  const int b0   = group * BPG;
  unsigned* ctr  = barriers + group * BAR_STRIDE;

  // ---- layer_w slice into registers: W[d, 128c .. 128c+128)
  float wreg[128];
  {
    const float4* ws = (const float4*)(lw + (size_t)d * DIMR + c * 128);
#pragma unroll
    for (int j = 0; j < 32; ++j) {
      float4 v = ws[j];
      wreg[4 * j + 0] = v.x; wreg[4 * j + 1] = v.y;
      wreg[4 * j + 2] = v.z; wreg[4 * j + 3] = v.w;
    }
  }
  // ---- input_w slice: cols [40c, 40c+40), zero-padded past 300
  float ireg[40];
#pragma unroll
  for (int j = 0; j < 40; ++j) {
    int i = c * 40 + j;
    ireg[j] = (i < INDIM) ? inw[(size_t)d * INDIM + i] : 0.f;
  }
  const float biasr = bias[d];

  // ---- lengths for our 4 batches (written by kernel 1 into out tail)
  float lenf[BPG];
#pragma unroll
  for (int b = 0; b < BPG; ++b)
    lenf[b] = out[(size_t)BSZ * TSTEPS * DIMR + b0 + b];

  // ---- init LDS: broadcast x0 (swizzled), zero ebuf pads, load emb t=0
  if (tid < 256) {
    float4 v = ((const float4*)x0)[tid];
    int k  = tid * 4;
    int ph = k ^ (((k >> 7) & 7) << 2);
#pragma unroll
    for (int b = 0; b < BPG; ++b) *(float4*)&xbuf[b][ph] = v;
  }
  if (tid < 160) {  // 2 bufs * 4 batches * 20 pad floats
    int bufi = tid / 80, rem = tid % 80;
    ebuf[bufi][rem / 20][300 + rem % 20] = 0.f;
  }
  if (tid < 300) {  // 300 float4s = 4 batches * 75
    int b = tid / 75, q = tid % 75;
    float4 v = *(const float4*)(emb + ((size_t)(b0 + b)) * INDIM + q * 4);
    *(float4*)&ebuf[0][b][q * 4] = v;
  }
  __syncthreads();

  for (int t = 0; t < TSTEPS; ++t) {
    const int cur = t & 1, nxt = cur ^ 1;

    // prefetch next emb tile into registers (hides HBM under the dots)
    float4 pf; int pb = 0, pq = 0;
    const bool do_pf = (t + 1 < TSTEPS) && (tid < 300);
    if (do_pf) {
      pb = tid / 75; pq = tid % 75;
      pf = *(const float4*)(emb +
            ((size_t)(t + 1) * BSZ + b0 + pb) * INDIM + pq * 4);
    }

    // ---- dots: recurrent (swizzled LDS reads, conflict-free) + input part
    float acc[BPG];
#pragma unroll
    for (int b = 0; b < BPG; ++b) {
      float a = 0.f;
#pragma unroll
      for (int j4 = 0; j4 < 32; ++j4) {
        const float4 xv = *(const float4*)&xbuf[b][c * 128 + 4 * (j4 ^ c)];
        a = fmaf(wreg[4 * j4 + 0], xv.x, a);
        a = fmaf(wreg[4 * j4 + 1], xv.y, a);
        a = fmaf(wreg[4 * j4 + 2], xv.z, a);
        a = fmaf(wreg[4 * j4 + 3], xv.w, a);
      }
#pragma unroll
      for (int j4 = 0; j4 < 10; ++j4) {
        const float4 ev = *(const float4*)&ebuf[cur][b][c * 40 + 4 * j4];
        a = fmaf(ireg[4 * j4 + 0], ev.x, a);
        a = fmaf(ireg[4 * j4 + 1], ev.y, a);
        a = fmaf(ireg[4 * j4 + 2], ev.z, a);
        a = fmaf(ireg[4 * j4 + 3], ev.w, a);
      }
      acc[b] = a;
    }

    // ---- reduce across the 8 chunk lanes; lane c==b keeps batch b
    float val = 0.f;
#pragma unroll
    for (int b = 0; b < BPG; ++b) {
      float p = acc[b];
      p += __shfl_xor(p, 1, 64);
      p += __shfl_xor(p, 2, 64);
      p += __shfl_xor(p, 4, 64);
      if (c == b) val = p;
    }

    // ---- finalize + store (d_out is also the exchange buffer)
    if (c < BPG) {
      float u  = val + biasr;
      float h  = tanhf(u);
      int   ph = d ^ (((d >> 7) & 7) << 2);
      float xo = xbuf[c][ph];
      float xn = LEAKF * h + (1.f - LEAKF) * xo;
      if ((float)t >= lenf[c]) xn = 0.f;
      out[((size_t)(b0 + c) * TSTEPS + t) * DIMR + d] = xn;
    }

    // stash prefetched emb into the other LDS buffer
    if (do_pf) *(float4*)&ebuf[nxt][pb][pq * 4] = pf;

    // ---- publish stores, group barrier (16 arrivals per step)
    __threadfence();
    __syncthreads();
    if (tid == 0) {
      __hip_atomic_fetch_add(ctr, 1u, __ATOMIC_RELEASE,
                             __HIP_MEMORY_SCOPE_AGENT);
      const unsigned target = (unsigned)(t + 1) * WPG;
      while (__hip_atomic_load(ctr, __ATOMIC_ACQUIRE,
                               __HIP_MEMORY_SCOPE_AGENT) < target) { }
    }
    __syncthreads();

    // ---- reload full x_{t+1} (4 batches x 1024) from d_out into LDS
#pragma unroll
    for (int r = 0; r < 2; ++r) {
      int idx = tid + r * WGSZ;       // 0..1023 float4 index
      int b   = idx >> 8;
      int q   = idx & 255;
      float4 v = *(const float4*)(out +
                 ((size_t)(b0 + b) * TSTEPS + t) * DIMR + q * 4);
      int k  = q * 4;
      int ph = k ^ (((k >> 7) & 7) << 2);
      *(float4*)&xbuf[b][ph] = v;
    }
    __syncthreads();
  }
}

// ---------------------------------------------------------------------------
extern "C" void kernel_launch(void* const* d_in, const int* in_sizes, int n_in,
                              void* d_out, int out_size, void* d_ws,
                              size_t ws_size, hipStream_t stream) {
  const float* emb  = (const float*)d_in[0];
  const float* inw  = (const float*)d_in[1];
  const float* lw   = (const float*)d_in[2];
  const float* bias = (const float*)d_in[3];
  const float* x0   = (const float*)d_in[4];
  float* out = (float*)d_out;
  unsigned* barriers = (unsigned*)d_ws;

  hipLaunchKernelGGL(lengths_init_kernel, dim3(BSZ), dim3(256), 0, stream,
                     emb, out, barriers);
  hipLaunchKernelGGL(esn_recurrent_kernel, dim3(GROUPS * WPG), dim3(WGSZ), 0,
                     stream, emb, inw, lw, bias, x0, out, barriers);
}

// Round 5
// 10921.626 us; speedup vs baseline: 1.9511x; 1.9511x over previous
//
#include <hip/hip_runtime.h>

#define DIMR   1024
#define BSZ    64
#define TSTEPS 512
#define INDIM  300
#define LEAKF  0.5f

#define GROUPS 16   // batch groups
#define WPG    16   // workgroups per group
#define BPG    4    // batches per group
#define WGSZ   512  // threads per workgroup
#define BAR_STRIDE 64  // uints between group flag blocks (256B: 16 flags = one 64B line)

// ---------------------------------------------------------------------------
// Kernel 1: compute lengths[b] into the tail of d_out (as float), and zero the
// group flag words in d_ws (ws is re-poisoned 0xAA before every launch).
// ---------------------------------------------------------------------------
__global__ void lengths_init_kernel(const float* __restrict__ emb,
                                    float* __restrict__ out,
                                    unsigned* __restrict__ barriers) {
  const int b   = blockIdx.x;
  const int tid = threadIdx.x;
  if (b == 0) {
    for (int i = tid; i < GROUPS * BAR_STRIDE; i += 256) barriers[i] = 0u;
  }
  const int wave = tid >> 6, lane = tid & 63;
  int cnt = 0;
  for (int t = wave; t < TSTEPS; t += 4) {
    const float* row = emb + ((size_t)t * BSZ + b) * INDIM;
    float s = 0.f;
    for (int i = lane; i < INDIM; i += 64) s += row[i];
#pragma unroll
    for (int m = 32; m >= 1; m >>= 1) s += __shfl_xor(s, m, 64);
    if (s != 0.f) ++cnt;
  }
  __shared__ int part[4];
  if (lane == 0) part[wave] = cnt;
  __syncthreads();
  if (tid == 0)
    out[(size_t)BSZ * TSTEPS * DIMR + b] =
        (float)(part[0] + part[1] + part[2] + part[3]);
}

// ---------------------------------------------------------------------------
// Kernel 2: persistent recurrent kernel.
// Grid: 256 wgs x 512 thr. Group g (16 wgs) owns batches [4g,4g+4).
// wg slice s owns rows [64s, 64s+64) of layer_w, held in registers/AGPRs
// (lane: row d = 64s + 8*wave + (lane>>3), cols [128c,128c+128), c=lane&7).
// Per step: dot + shfl-reduce over the 8 chunk lanes -> tanh/leak/mask ->
// store to d_out (which doubles as the x exchange buffer) -> flag barrier:
//   one RELEASE store per wg + RELAXED 16-lane poll + one ACQUIRE fence
// (v1's per-thread __threadfence + acquire-spin + 16 serialized RMWs cost
//  ~34 us/step in L2 writeback/invalidate storms) -> reload x from d_out.
// ---------------------------------------------------------------------------
__global__ __launch_bounds__(WGSZ, 2) void esn_recurrent_kernel(
    const float* __restrict__ emb,
    const float* __restrict__ inw,
    const float* __restrict__ lw,
    const float* __restrict__ bias,
    const float* __restrict__ x0,
    float* __restrict__ out,
    unsigned* __restrict__ barriers) {

  __shared__ float xbuf[BPG][DIMR];     // current state, XOR-swizzled
  __shared__ float ebuf[2][BPG][320];   // emb tiles, padded 300->320 (pads=0)

  const int bid = blockIdx.x;
  const int xcd = bid & 7;
  const int ix  = bid >> 3;               // 0..31
  const int group = xcd * 2 + (ix & 1);   // 0..15 (16 wgs of a group share an XCD)
  const int slice = ix >> 1;              // 0..15
  const int tid  = threadIdx.x;
  const int w    = tid >> 6;
  const int lane = tid & 63;
  const int rl   = lane >> 3;
  const int c    = lane & 7;
  const int d    = slice * 64 + w * 8 + rl;
  const int b0   = group * BPG;
  unsigned* flg  = barriers + group * BAR_STRIDE;

  // ---- layer_w slice into registers: W[d, 128c .. 128c+128)
  float wreg[128];
  {
    const float4* ws = (const float4*)(lw + (size_t)d * DIMR + c * 128);
#pragma unroll
    for (int j = 0; j < 32; ++j) {
      float4 v = ws[j];
      wreg[4 * j + 0] = v.x; wreg[4 * j + 1] = v.y;
      wreg[4 * j + 2] = v.z; wreg[4 * j + 3] = v.w;
    }
  }
  // ---- input_w slice: cols [40c, 40c+40), zero-padded past 300
  float ireg[40];
#pragma unroll
  for (int j = 0; j < 40; ++j) {
    int i = c * 40 + j;
    ireg[j] = (i < INDIM) ? inw[(size_t)d * INDIM + i] : 0.f;
  }
  const float biasr = bias[d];

  // ---- lengths for our 4 batches (written by kernel 1 into out tail)
  float lenf[BPG];
#pragma unroll
  for (int b = 0; b < BPG; ++b)
    lenf[b] = out[(size_t)BSZ * TSTEPS * DIMR + b0 + b];

  // ---- init LDS: broadcast x0 (swizzled), zero ebuf pads, load emb t=0
  if (tid < 256) {
    float4 v = ((const float4*)x0)[tid];
    int k  = tid * 4;
    int ph = k ^ (((k >> 7) & 7) << 2);
#pragma unroll
    for (int b = 0; b < BPG; ++b) *(float4*)&xbuf[b][ph] = v;
  }
  if (tid < 160) {  // 2 bufs * 4 batches * 20 pad floats
    int bufi = tid / 80, rem = tid % 80;
    ebuf[bufi][rem / 20][300 + rem % 20] = 0.f;
  }
  if (tid < 300) {  // 300 float4s = 4 batches * 75
    int b = tid / 75, q = tid % 75;
    float4 v = *(const float4*)(emb + ((size_t)(b0 + b)) * INDIM + q * 4);
    *(float4*)&ebuf[0][b][q * 4] = v;
  }
  __syncthreads();

  for (int t = 0; t < TSTEPS; ++t) {
    const int cur = t & 1, nxt = cur ^ 1;

    // prefetch next emb tile into registers (hides HBM under the dots)
    float4 pf; int pb = 0, pq = 0;
    const bool do_pf = (t + 1 < TSTEPS) && (tid < 300);
    if (do_pf) {
      pb = tid / 75; pq = tid % 75;
      pf = *(const float4*)(emb +
            ((size_t)(t + 1) * BSZ + b0 + pb) * INDIM + pq * 4);
    }

    // ---- dots: recurrent (swizzled LDS reads, conflict-free) + input part
    float acc[BPG];
#pragma unroll
    for (int b = 0; b < BPG; ++b) {
      float a = 0.f;
#pragma unroll
      for (int j4 = 0; j4 < 32; ++j4) {
        const float4 xv = *(const float4*)&xbuf[b][c * 128 + 4 * (j4 ^ c)];
        a = fmaf(wreg[4 * j4 + 0], xv.x, a);
        a = fmaf(wreg[4 * j4 + 1], xv.y, a);
        a = fmaf(wreg[4 * j4 + 2], xv.z, a);
        a = fmaf(wreg[4 * j4 + 3], xv.w, a);
      }
#pragma unroll
      for (int j4 = 0; j4 < 10; ++j4) {
        const float4 ev = *(const float4*)&ebuf[cur][b][c * 40 + 4 * j4];
        a = fmaf(ireg[4 * j4 + 0], ev.x, a);
        a = fmaf(ireg[4 * j4 + 1], ev.y, a);
        a = fmaf(ireg[4 * j4 + 2], ev.z, a);
        a = fmaf(ireg[4 * j4 + 3], ev.w, a);
      }
      acc[b] = a;
    }

    // ---- reduce across the 8 chunk lanes; lane c==b keeps batch b
    float val = 0.f;
#pragma unroll
    for (int b = 0; b < BPG; ++b) {
      float p = acc[b];
      p += __shfl_xor(p, 1, 64);
      p += __shfl_xor(p, 2, 64);
      p += __shfl_xor(p, 4, 64);
      if (c == b) val = p;
    }

    // ---- finalize + store (d_out is also the exchange buffer)
    if (c < BPG) {
      float u  = val + biasr;
      float h  = tanhf(u);
      int   ph = d ^ (((d >> 7) & 7) << 2);
      float xo = xbuf[c][ph];
      float xn = LEAKF * h + (1.f - LEAKF) * xo;
      if ((float)t >= lenf[c]) xn = 0.f;
      out[((size_t)(b0 + c) * TSTEPS + t) * DIMR + d] = xn;
    }

    // stash prefetched emb into the other LDS buffer
    if (do_pf) *(float4*)&ebuf[nxt][pb][pq * 4] = pf;

    // ---- drain all waves' stores to L2 (syncthreads emits vmcnt(0)/wave)
    __syncthreads();

    if (t + 1 < TSTEPS) {
      const unsigned tgt = (unsigned)(t + 1);
      // arrival: ONE release store per wg (wbl2 once; wave already drained).
      // Same wave as the pollers -> store branch executes before poll branch.
      if (tid == 16)
        __hip_atomic_store(&flg[slice], tgt, __ATOMIC_RELEASE,
                           __HIP_MEMORY_SCOPE_AGENT);
      // wait: lanes 0-15 poll the 16 flags (one 64B line, ONE wave load per
      // iteration, RELAXED -> no per-poll cache invalidates).
      if (tid < WPG) {
        while (__hip_atomic_load(&flg[tid], __ATOMIC_RELAXED,
                                 __HIP_MEMORY_SCOPE_AGENT) < tgt)
          __builtin_amdgcn_s_sleep(2);
      }
      // one acquire fence: orders + invalidates L1/L2 once per wave per step
      __builtin_amdgcn_fence(__ATOMIC_ACQUIRE, "agent");
      __syncthreads();   // nobody reloads until wave 0's poll is done

      // ---- reload full x_{t+1} (4 batches x 1024) from d_out into LDS
#pragma unroll
      for (int r = 0; r < 2; ++r) {
        int idx = tid + r * WGSZ;       // 0..1023 float4 index
        int b   = idx >> 8;
        int q   = idx & 255;
        float4 v = *(const float4*)(out +
                   ((size_t)(b0 + b) * TSTEPS + t) * DIMR + q * 4);
        int k  = q * 4;
        int ph = k ^ (((k >> 7) & 7) << 2);
        *(float4*)&xbuf[b][ph] = v;
      }
      __syncthreads();
    }
  }
}

// ---------------------------------------------------------------------------
extern "C" void kernel_launch(void* const* d_in, const int* in_sizes, int n_in,
                              void* d_out, int out_size, void* d_ws,
                              size_t ws_size, hipStream_t stream) {
  const float* emb  = (const float*)d_in[0];
  const float* inw  = (const float*)d_in[1];
  const float* lw   = (const float*)d_in[2];
  const float* bias = (const float*)d_in[3];
  const float* x0   = (const float*)d_in[4];
  float* out = (float*)d_out;
  unsigned* barriers = (unsigned*)d_ws;

  hipLaunchKernelGGL(lengths_init_kernel, dim3(BSZ), dim3(256), 0, stream,
                     emb, out, barriers);
  hipLaunchKernelGGL(esn_recurrent_kernel, dim3(GROUPS * WPG), dim3(WGSZ), 0,
                     stream, emb, inw, lw, bias, x0, out, barriers);
}

// Round 6
// 3431.969 us; speedup vs baseline: 6.2090x; 3.1823x over previous
//
#include <hip/hip_runtime.h>

#define DIMR   1024
#define BSZ    64
#define TSTEPS 512
#define INDIM  300
#define LEAKF  0.5f

#define GROUPS 16   // batch groups
#define WPG    16   // workgroups per group
#define BPG    4    // batches per group
#define WGSZ   512  // threads per workgroup
#define BAR_STRIDE 64  // uints between group flag blocks (256B: 16 flags = one 64B line)

// ---------------------------------------------------------------------------
// Kernel 1: compute lengths[b] into the tail of d_out (as float), and zero the
// group flag words in d_ws (ws is re-poisoned 0xAA before every launch).
// ---------------------------------------------------------------------------
__global__ void lengths_init_kernel(const float* __restrict__ emb,
                                    float* __restrict__ out,
                                    unsigned* __restrict__ barriers) {
  const int b   = blockIdx.x;
  const int tid = threadIdx.x;
  if (b == 0) {
    for (int i = tid; i < GROUPS * BAR_STRIDE; i += 256) barriers[i] = 0u;
  }
  const int wave = tid >> 6, lane = tid & 63;
  int cnt = 0;
  for (int t = wave; t < TSTEPS; t += 4) {
    const float* row = emb + ((size_t)t * BSZ + b) * INDIM;
    float s = 0.f;
    for (int i = lane; i < INDIM; i += 64) s += row[i];
#pragma unroll
    for (int m = 32; m >= 1; m >>= 1) s += __shfl_xor(s, m, 64);
    if (s != 0.f) ++cnt;
  }
  __shared__ int part[4];
  if (lane == 0) part[wave] = cnt;
  __syncthreads();
  if (tid == 0)
    out[(size_t)BSZ * TSTEPS * DIMR + b] =
        (float)(part[0] + part[1] + part[2] + part[3]);
}

// ---------------------------------------------------------------------------
// Kernel 2: persistent recurrent kernel.
// Grid: 256 wgs x 512 thr. Group g (16 wgs) owns batches [4g,4g+4).
// wg slice s owns rows [64s, 64s+64) of layer_w in registers/AGPRs.
//
// Sync protocol v3 (FENCE-FREE): exchange data, flags, polls and reloads are
// ALL system-scope RELAXED atomics (sc0 sc1 -> bypass L1/L2, live at L3).
// No dirty L2 copies of exchange data exist, so the RELEASE wbl2 (full 4MiB
// L2 tag-walk writeback) and ACQUIRE buffer_inv (tag-walk invalidate) that
// cost ~13us/step in v2 are eliminated. __syncthreads()'s vmcnt(0) drains
// the write-through stores to the coherence point before the flag store.
// ---------------------------------------------------------------------------
__global__ __launch_bounds__(WGSZ, 2) void esn_recurrent_kernel(
    const float* __restrict__ emb,
    const float* __restrict__ inw,
    const float* __restrict__ lw,
    const float* __restrict__ bias,
    const float* __restrict__ x0,
    float* __restrict__ out,
    unsigned* __restrict__ barriers) {

  __shared__ float xbuf[BPG][DIMR];     // current state, XOR-swizzled
  __shared__ float ebuf[2][BPG][320];   // emb tiles, padded 300->320 (pads=0)

  const int bid = blockIdx.x;
  const int xcd = bid & 7;
  const int ix  = bid >> 3;               // 0..31
  const int group = xcd * 2 + (ix & 1);   // 0..15 (16 wgs of a group share an XCD)
  const int slice = ix >> 1;              // 0..15
  const int tid  = threadIdx.x;
  const int w    = tid >> 6;
  const int lane = tid & 63;
  const int rl   = lane >> 3;
  const int c    = lane & 7;
  const int d    = slice * 64 + w * 8 + rl;
  const int b0   = group * BPG;
  unsigned* flg  = barriers + group * BAR_STRIDE;

  // ---- layer_w slice into registers: W[d, 128c .. 128c+128)
  float wreg[128];
  {
    const float4* ws = (const float4*)(lw + (size_t)d * DIMR + c * 128);
#pragma unroll
    for (int j = 0; j < 32; ++j) {
      float4 v = ws[j];
      wreg[4 * j + 0] = v.x; wreg[4 * j + 1] = v.y;
      wreg[4 * j + 2] = v.z; wreg[4 * j + 3] = v.w;
    }
  }
  // ---- input_w slice: cols [40c, 40c+40), zero-padded past 300
  float ireg[40];
#pragma unroll
  for (int j = 0; j < 40; ++j) {
    int i = c * 40 + j;
    ireg[j] = (i < INDIM) ? inw[(size_t)d * INDIM + i] : 0.f;
  }
  const float biasr = bias[d];

  // ---- lengths for our 4 batches (written by kernel 1 into out tail)
  float lenf[BPG];
#pragma unroll
  for (int b = 0; b < BPG; ++b)
    lenf[b] = out[(size_t)BSZ * TSTEPS * DIMR + b0 + b];

  // ---- init LDS: broadcast x0 (swizzled), zero ebuf pads, load emb t=0
  if (tid < 256) {
    float4 v = ((const float4*)x0)[tid];
    int k  = tid * 4;
    int ph = k ^ (((k >> 7) & 7) << 2);
#pragma unroll
    for (int b = 0; b < BPG; ++b) *(float4*)&xbuf[b][ph] = v;
  }
  if (tid < 160) {  // 2 bufs * 4 batches * 20 pad floats
    int bufi = tid / 80, rem = tid % 80;
    ebuf[bufi][rem / 20][300 + rem % 20] = 0.f;
  }
  if (tid < 300) {  // 300 float4s = 4 batches * 75
    int b = tid / 75, q = tid % 75;
    float4 v = *(const float4*)(emb + ((size_t)(b0 + b)) * INDIM + q * 4);
    *(float4*)&ebuf[0][b][q * 4] = v;
  }
  __syncthreads();

  for (int t = 0; t < TSTEPS; ++t) {
    const int cur = t & 1, nxt = cur ^ 1;

    // prefetch next emb tile into registers (hides HBM under the dots)
    float4 pf; int pb = 0, pq = 0;
    const bool do_pf = (t + 1 < TSTEPS) && (tid < 300);
    if (do_pf) {
      pb = tid / 75; pq = tid % 75;
      pf = *(const float4*)(emb +
            ((size_t)(t + 1) * BSZ + b0 + pb) * INDIM + pq * 4);
    }

    // ---- dots: recurrent (swizzled LDS reads, conflict-free) + input part
    float acc[BPG];
#pragma unroll
    for (int b = 0; b < BPG; ++b) {
      float a = 0.f;
#pragma unroll
      for (int j4 = 0; j4 < 32; ++j4) {
        const float4 xv = *(const float4*)&xbuf[b][c * 128 + 4 * (j4 ^ c)];
        a = fmaf(wreg[4 * j4 + 0], xv.x, a);
        a = fmaf(wreg[4 * j4 + 1], xv.y, a);
        a = fmaf(wreg[4 * j4 + 2], xv.z, a);
        a = fmaf(wreg[4 * j4 + 3], xv.w, a);
      }
#pragma unroll
      for (int j4 = 0; j4 < 10; ++j4) {
        const float4 ev = *(const float4*)&ebuf[cur][b][c * 40 + 4 * j4];
        a = fmaf(ireg[4 * j4 + 0], ev.x, a);
        a = fmaf(ireg[4 * j4 + 1], ev.y, a);
        a = fmaf(ireg[4 * j4 + 2], ev.z, a);
        a = fmaf(ireg[4 * j4 + 3], ev.w, a);
      }
      acc[b] = a;
    }

    // ---- reduce across the 8 chunk lanes; lane c==b keeps batch b
    float val = 0.f;
#pragma unroll
    for (int b = 0; b < BPG; ++b) {
      float p = acc[b];
      p += __shfl_xor(p, 1, 64);
      p += __shfl_xor(p, 2, 64);
      p += __shfl_xor(p, 4, 64);
      if (c == b) val = p;
    }

    // ---- finalize + store (d_out is also the exchange buffer)
    // System-scope relaxed store: write-through to L3 (sc0 sc1), so readers
    // on other CUs/XCDs see it without any cache-flush fence.
    if (c < BPG) {
      float u  = val + biasr;
      float h  = tanhf(u);
      int   ph = d ^ (((d >> 7) & 7) << 2);
      float xo = xbuf[c][ph];
      float xn = LEAKF * h + (1.f - LEAKF) * xo;
      if ((float)t >= lenf[c]) xn = 0.f;
      __hip_atomic_store(&out[((size_t)(b0 + c) * TSTEPS + t) * DIMR + d], xn,
                         __ATOMIC_RELAXED, __HIP_MEMORY_SCOPE_SYSTEM);
    }

    // stash prefetched emb into the other LDS buffer
    if (do_pf) *(float4*)&ebuf[nxt][pb][pq * 4] = pf;

    // ---- all waves' write-through stores drained at barrier (vmcnt(0))
    __syncthreads();

    if (t + 1 < TSTEPS) {
      const unsigned tgt = (unsigned)(t + 1);
      // arrival: one system-relaxed flag store per wg (no wbl2 — data already
      // at the coherence point). Store branch precedes poll branch in-wave.
      if (tid == 16)
        __hip_atomic_store(&flg[slice], tgt, __ATOMIC_RELAXED,
                           __HIP_MEMORY_SCOPE_SYSTEM);
      // wait: lanes 0-15 poll the 16 flags (one 64B line, one wave load per
      // iteration, relaxed system loads read L3 directly -> never stale).
      if (tid < WPG) {
        while (__hip_atomic_load(&flg[tid], __ATOMIC_RELAXED,
                                 __HIP_MEMORY_SCOPE_SYSTEM) < tgt)
          __builtin_amdgcn_s_sleep(2);
      }
      // compiler-ordering only (workgroup scope: no L2 tag-walk invalidate)
      __builtin_amdgcn_fence(__ATOMIC_ACQUIRE, "workgroup");
      __syncthreads();   // nobody reloads until wave 0's poll is done

      // ---- reload full x_{t+1} (4 batches x 1024) from d_out into LDS.
      // System-relaxed scalar loads bypass L1/L2 -> read the L3-resident
      // fresh data; compiler tracks their vmcnt (no inline-asm hazards).
#pragma unroll
      for (int r = 0; r < 2; ++r) {
        int idx = tid + r * WGSZ;       // 0..1023 float4 index
        int b   = idx >> 8;
        int q   = idx & 255;
        const float* src = out + ((size_t)(b0 + b) * TSTEPS + t) * DIMR + q * 4;
        float4 v;
        v.x = __hip_atomic_load(src + 0, __ATOMIC_RELAXED, __HIP_MEMORY_SCOPE_SYSTEM);
        v.y = __hip_atomic_load(src + 1, __ATOMIC_RELAXED, __HIP_MEMORY_SCOPE_SYSTEM);
        v.z = __hip_atomic_load(src + 2, __ATOMIC_RELAXED, __HIP_MEMORY_SCOPE_SYSTEM);
        v.w = __hip_atomic_load(src + 3, __ATOMIC_RELAXED, __HIP_MEMORY_SCOPE_SYSTEM);
        int k  = q * 4;
        int ph = k ^ (((k >> 7) & 7) << 2);
        *(float4*)&xbuf[b][ph] = v;
      }
      __syncthreads();
    }
  }
}

// ---------------------------------------------------------------------------
extern "C" void kernel_launch(void* const* d_in, const int* in_sizes, int n_in,
                              void* d_out, int out_size, void* d_ws,
                              size_t ws_size, hipStream_t stream) {
  const float* emb  = (const float*)d_in[0];
  const float* inw  = (const float*)d_in[1];
  const float* lw   = (const float*)d_in[2];
  const float* bias = (const float*)d_in[3];
  const float* x0   = (const float*)d_in[4];
  float* out = (float*)d_out;
  unsigned* barriers = (unsigned*)d_ws;

  hipLaunchKernelGGL(lengths_init_kernel, dim3(BSZ), dim3(256), 0, stream,
                     emb, out, barriers);
  hipLaunchKernelGGL(esn_recurrent_kernel, dim3(GROUPS * WPG), dim3(WGSZ), 0,
                     stream, emb, inw, lw, bias, x0, out, barriers);
}

// Round 7
// 3153.446 us; speedup vs baseline: 6.7574x; 1.0883x over previous
//
#include <hip/hip_runtime.h>

#define DIMR   1024
#define BSZ    64
#define TSTEPS 512
#define INDIM  300
#define EPAD   384          // emb K padded to 12 slices of 32
#define LEAKF  0.5f

#define GROUPS 16   // batch groups
#define WPG    16   // workgroups per group
#define BPG    4    // batches per group
#define WGSZ   512  // 8 waves
#define BAR_STRIDE 64

typedef __attribute__((ext_vector_type(8))) short short8;
typedef __attribute__((ext_vector_type(4))) short short4v;
typedef __attribute__((ext_vector_type(4))) float f32x4;

// byte offset of bf16 element (row, k) in the swizzled LDS A-tiles
#define AX_BYTE(r, k) ((((r) * 2048) + ((k) * 2)) ^ (((r) & 7) << 4))
#define AE_BYTE(r, k) ((((r) * (EPAD * 2)) + ((k) * 2)) ^ (((r) & 7) << 4))

__device__ __forceinline__ unsigned short f2bf(float f) {  // RNE f32->bf16
  unsigned u = __float_as_uint(f);
  u += 0x7FFFu + ((u >> 16) & 1u);
  return (unsigned short)(u >> 16);
}
__device__ __forceinline__ short8 pack8(const float* f) {
  short8 r;
  r[0] = (short)f2bf(f[0]); r[1] = (short)f2bf(f[1]);
  r[2] = (short)f2bf(f[2]); r[3] = (short)f2bf(f[3]);
  r[4] = (short)f2bf(f[4]); r[5] = (short)f2bf(f[5]);
  r[6] = (short)f2bf(f[6]); r[7] = (short)f2bf(f[7]);
  return r;
}

// ---------------------------------------------------------------------------
// Kernel 1: lengths -> out tail (f32); zero barrier flags in d_ws.
// ---------------------------------------------------------------------------
__global__ void lengths_init_kernel(const float* __restrict__ emb,
                                    float* __restrict__ out,
                                    unsigned* __restrict__ barriers) {
  const int b   = blockIdx.x;
  const int tid = threadIdx.x;
  if (b == 0) {
    for (int i = tid; i < GROUPS * BAR_STRIDE; i += 256) barriers[i] = 0u;
  }
  const int wave = tid >> 6, lane = tid & 63;
  int cnt = 0;
  for (int t = wave; t < TSTEPS; t += 4) {
    const float* row = emb + ((size_t)t * BSZ + b) * INDIM;
    float s = 0.f;
    for (int i = lane; i < INDIM; i += 64) s += row[i];
#pragma unroll
    for (int m = 32; m >= 1; m >>= 1) s += __shfl_xor(s, m, 64);
    if (s != 0.f) ++cnt;
  }
  __shared__ int part[4];
  if (lane == 0) part[wave] = cnt;
  __syncthreads();
  if (tid == 0)
    out[(size_t)BSZ * TSTEPS * DIMR + b] =
        (float)(part[0] + part[1] + part[2] + part[3]);
}

// ---------------------------------------------------------------------------
// Kernel 2: persistent MFMA recurrent kernel.
// Grid 256 wgs x 512 thr. Group g (16 wgs) owns batches [4g,4g+4); wg slice
// owns 64 rows of W as bf16 B-fragments in VGPRs. x lives in LDS as a bf16
// A-tile [16 rows][1024] (rows 0-3 = batches, 4-15 zero), XOR-swizzled.
// 8 waves = tile-pair p (tiles 2p,2p+1 of 16 cols) x K-quarter q. Per step:
// 22 mfma_f32_16x16x32_bf16 per wave -> LDS-reduce quarters -> q==0 waves
// finalize (bias+tanh+leak+mask, x_old in f32 regs) -> system-scope store to
// d_out -> v3 flag barrier (proven round 6) -> reload x as bf16 into LDS.
// ---------------------------------------------------------------------------
__global__ __launch_bounds__(WGSZ, 2) void esn_recurrent_kernel(
    const float* __restrict__ emb,
    const float* __restrict__ inw,
    const float* __restrict__ lw,
    const float* __restrict__ bias,
    const float* __restrict__ x0,
    float* __restrict__ out,
    unsigned* __restrict__ barriers) {

  __shared__ __align__(16) unsigned short a_x[16 * 1024];    // 32 KB, swizzled
  __shared__ __align__(16) unsigned short aemb[2][16 * EPAD]; // 24 KB, swizzled
  __shared__ __align__(16) float red[3][4][16][4];            // 3 KB partials

  const int bid   = blockIdx.x;
  const int xcd   = bid & 7;
  const int ix    = bid >> 3;
  const int group = xcd * 2 + (ix & 1);
  const int slice = ix >> 1;
  const int wg_row0 = slice * 64;
  const int tid = threadIdx.x;
  const int w   = tid >> 6, l = tid & 63;
  const int c15 = l & 15, kg = l >> 4;     // A row / B col ; k-group
  const int p   = w & 1;                   // tile-pair: tiles 2p, 2p+1
  const int q   = w >> 1;                  // K-quarter 0..3
  const int b0  = group * BPG;
  unsigned* flg = barriers + group * BAR_STRIDE;

  // ---- B-fragments: W rows (bf16) for this wave's two tiles, K-quarter q
  const int dB0 = wg_row0 + (2 * p) * 16 + c15;
  const int dB1 = dB0 + 16;
  short8 wB[2][8];   // layer_w: 8 slices of K=32
  short8 wE[2][3];   // input_w: 3 slices (K padded 300->384)
#pragma unroll
  for (int tt = 0; tt < 2; ++tt) {
    const int dB = tt ? dB1 : dB0;
#pragma unroll
    for (int s = 0; s < 8; ++s) {
      const int k = q * 256 + s * 32 + kg * 8;
      const float* src = lw + (size_t)dB * DIMR + k;
      float tmp[8];
      float4 f0 = *(const float4*)(src);
      float4 f1 = *(const float4*)(src + 4);
      tmp[0] = f0.x; tmp[1] = f0.y; tmp[2] = f0.z; tmp[3] = f0.w;
      tmp[4] = f1.x; tmp[5] = f1.y; tmp[6] = f1.z; tmp[7] = f1.w;
      wB[tt][s] = pack8(tmp);
    }
#pragma unroll
    for (int se = 0; se < 3; ++se) {
      const int ke = q * 96 + se * 32 + kg * 8;
      float tmp[8];
#pragma unroll
      for (int j = 0; j < 8; ++j)
        tmp[j] = (ke + j < INDIM) ? inw[(size_t)dB * INDIM + ke + j] : 0.f;
      wE[tt][se] = pack8(tmp);
    }
  }
  const float bias0 = bias[dB0], bias1 = bias[dB1];

  // lengths + running state (meaningful in q==0 waves, lanes 0-15)
  float lenf[BPG];
#pragma unroll
  for (int b = 0; b < BPG; ++b)
    lenf[b] = out[(size_t)BSZ * TSTEPS * DIMR + b0 + b];
  float xo0[4], xo1[4];
  {
    const float xa = x0[dB0], xb = x0[dB1];
#pragma unroll
    for (int r = 0; r < 4; ++r) { xo0[r] = xa; xo1[r] = xb; }
  }

  // ---- init LDS: zero a_x rows 4-15, zero all aemb, x0 -> a_x rows 0-3
  {
    const short8 z = {0, 0, 0, 0, 0, 0, 0, 0};
    for (int u = 512 + tid; u < 2048; u += WGSZ)  // rows 4-15 of a_x
      *((short8*)a_x + u) = z;
    for (int u = tid; u < 1536; u += WGSZ)        // all of aemb (both bufs)
      *((short8*)&aemb[0][0] + u) = z;
    const int r = tid >> 7, k0 = (tid & 127) * 8;
    float tmp[8];
#pragma unroll
    for (int j = 0; j < 8; ++j) tmp[j] = x0[k0 + j];
    *(short8*)((char*)a_x + AX_BYTE(r, k0)) = pack8(tmp);
  }
  __syncthreads();
  if (tid < 300) {  // emb t=0 -> aemb[0] rows 0-3 (cols [0,300))
    const int pb = tid / 75, pq = tid % 75;
    float4 v = *(const float4*)(emb + ((size_t)(b0 + pb)) * INDIM + pq * 4);
    short4v d;
    d[0] = (short)f2bf(v.x); d[1] = (short)f2bf(v.y);
    d[2] = (short)f2bf(v.z); d[3] = (short)f2bf(v.w);
    *(short4v*)((char*)&aemb[0][0] + AE_BYTE(pb, pq * 4)) = d;
  }
  __syncthreads();

  for (int t = 0; t < TSTEPS; ++t) {
    const int cur = t & 1, nxt = cur ^ 1;

    // emb prefetch for t+1 (global loads early; LDS write after barrier (b))
    float4 pf; int pb = 0, pq = 0;
    const bool do_pf = (t + 1 < TSTEPS) && (tid < 300);
    if (do_pf) {
      pb = tid / 75; pq = tid % 75;
      pf = *(const float4*)(emb +
            ((size_t)(t + 1) * BSZ + b0 + pb) * INDIM + pq * 4);
    }

    // ---- MFMA phase: this wave's K-quarter for tiles 2p, 2p+1
    f32x4 a00 = {0.f, 0.f, 0.f, 0.f}, a01 = a00, a10 = a00, a11 = a00;
    const char* axp = (const char*)a_x;
    const char* aep = (const char*)&aemb[cur][0];
#pragma unroll
    for (int s = 0; s < 8; ++s) {
      const int k = q * 256 + s * 32 + kg * 8;
      short8 af = *(const short8*)(axp + AX_BYTE(c15, k));
      if (s & 1) {
        a01 = __builtin_amdgcn_mfma_f32_16x16x32_bf16(af, wB[0][s], a01, 0, 0, 0);
        a11 = __builtin_amdgcn_mfma_f32_16x16x32_bf16(af, wB[1][s], a11, 0, 0, 0);
      } else {
        a00 = __builtin_amdgcn_mfma_f32_16x16x32_bf16(af, wB[0][s], a00, 0, 0, 0);
        a10 = __builtin_amdgcn_mfma_f32_16x16x32_bf16(af, wB[1][s], a10, 0, 0, 0);
      }
    }
#pragma unroll
    for (int se = 0; se < 3; ++se) {
      const int ke = q * 96 + se * 32 + kg * 8;
      short8 af = *(const short8*)(aep + AE_BYTE(c15, ke));
      if (se & 1) {
        a01 = __builtin_amdgcn_mfma_f32_16x16x32_bf16(af, wE[0][se], a01, 0, 0, 0);
        a11 = __builtin_amdgcn_mfma_f32_16x16x32_bf16(af, wE[1][se], a11, 0, 0, 0);
      } else {
        a00 = __builtin_amdgcn_mfma_f32_16x16x32_bf16(af, wE[0][se], a00, 0, 0, 0);
        a10 = __builtin_amdgcn_mfma_f32_16x16x32_bf16(af, wE[1][se], a10, 0, 0, 0);
      }
    }
    f32x4 c40 = a00 + a01;
    f32x4 c41 = a10 + a11;

    // ---- K-quarter partials -> LDS (quarters 1..3)
    if (q != 0 && l < 16) {
      *(f32x4*)&red[q - 1][2 * p + 0][l][0] = c40;
      *(f32x4*)&red[q - 1][2 * p + 1][l][0] = c41;
    }
    __syncthreads();                                  // (a)

    // ---- finalize by q==0 waves, lanes 0-15 (C rows 0-3 = batches)
    if (q == 0 && l < 16) {
#pragma unroll
      for (int qq = 0; qq < 3; ++qq) {
        c40 += *(const f32x4*)&red[qq][2 * p + 0][l][0];
        c41 += *(const f32x4*)&red[qq][2 * p + 1][l][0];
      }
#pragma unroll
      for (int r = 0; r < 4; ++r) {
        float u0 = c40[r] + bias0;
        float xn0 = LEAKF * tanhf(u0) + (1.f - LEAKF) * xo0[r];
        if ((float)t >= lenf[r]) xn0 = 0.f;
        xo0[r] = xn0;
        __hip_atomic_store(&out[((size_t)(b0 + r) * TSTEPS + t) * DIMR + dB0],
                           xn0, __ATOMIC_RELAXED, __HIP_MEMORY_SCOPE_SYSTEM);
        float u1 = c41[r] + bias1;
        float xn1 = LEAKF * tanhf(u1) + (1.f - LEAKF) * xo1[r];
        if ((float)t >= lenf[r]) xn1 = 0.f;
        xo1[r] = xn1;
        __hip_atomic_store(&out[((size_t)(b0 + r) * TSTEPS + t) * DIMR + dB1],
                           xn1, __ATOMIC_RELAXED, __HIP_MEMORY_SCOPE_SYSTEM);
      }
    }
    __syncthreads();                                  // (b) drains stores

    if (t + 1 < TSTEPS) {
      // stash prefetched emb into the other LDS buffer (read at t+1)
      if (do_pf) {
        short4v d;
        d[0] = (short)f2bf(pf.x); d[1] = (short)f2bf(pf.y);
        d[2] = (short)f2bf(pf.z); d[3] = (short)f2bf(pf.w);
        *(short4v*)((char*)&aemb[nxt][0] + AE_BYTE(pb, pq * 4)) = d;
      }
      const unsigned tgt = (unsigned)(t + 1);
      if (tid == 16)
        __hip_atomic_store(&flg[slice], tgt, __ATOMIC_RELAXED,
                           __HIP_MEMORY_SCOPE_SYSTEM);
      if (tid < WPG) {
        while (__hip_atomic_load(&flg[tid], __ATOMIC_RELAXED,
                                 __HIP_MEMORY_SCOPE_SYSTEM) < tgt)
          __builtin_amdgcn_s_sleep(2);
      }
      __builtin_amdgcn_fence(__ATOMIC_ACQUIRE, "workgroup");
      __syncthreads();                                // (c)

      // ---- reload x_{t+1}: 8 floats/thread -> bf16x8 -> swizzled a_x
      {
        const int r = tid >> 7, k0 = (tid & 127) * 8;
        const float* src = out + ((size_t)(b0 + r) * TSTEPS + t) * DIMR + k0;
        float tmp[8];
#pragma unroll
        for (int j = 0; j < 8; ++j)
          tmp[j] = __hip_atomic_load(src + j, __ATOMIC_RELAXED,
                                     __HIP_MEMORY_SCOPE_SYSTEM);
        *(short8*)((char*)a_x + AX_BYTE(r, k0)) = pack8(tmp);
      }
      __syncthreads();                                // (d)
    }
  }
}

// ---------------------------------------------------------------------------
extern "C" void kernel_launch(void* const* d_in, const int* in_sizes, int n_in,
                              void* d_out, int out_size, void* d_ws,
                              size_t ws_size, hipStream_t stream) {
  const float* emb  = (const float*)d_in[0];
  const float* inw  = (const float*)d_in[1];
  const float* lw   = (const float*)d_in[2];
  const float* bias = (const float*)d_in[3];
  const float* x0   = (const float*)d_in[4];
  float* out = (float*)d_out;
  unsigned* barriers = (unsigned*)d_ws;

  hipLaunchKernelGGL(lengths_init_kernel, dim3(BSZ), dim3(256), 0, stream,
                     emb, out, barriers);
  hipLaunchKernelGGL(esn_recurrent_kernel, dim3(GROUPS * WPG), dim3(WGSZ), 0,
                     stream, emb, inw, lw, bias, x0, out, barriers);
}

// Round 8
// 2171.601 us; speedup vs baseline: 9.8126x; 1.4521x over previous
//
#include <hip/hip_runtime.h>

#define DIMR   1024
#define BSZ    64
#define TSTEPS 512
#define INDIM  300
#define EPAD   320          // emb K padded to 10 slices of 32
#define LEAKF  0.5f

#define GROUPS 32   // batch groups (2 batches each)
#define WPG    8    // workgroups per group (one XCD)
#define BPG    2    // batches per group
#define WGSZ   512  // 8 waves

typedef __attribute__((ext_vector_type(8))) short short8;
typedef __attribute__((ext_vector_type(4))) short short4v;
typedef __attribute__((ext_vector_type(4))) float f32x4;

// byte offset of bf16 element (row, k) in the swizzled LDS A-tiles
#define AX_BYTE(r, k) ((((r) * 2048) + ((k) * 2)) ^ (((r) & 7) << 4))
#define AE_BYTE(r, k) ((((r) * (EPAD * 2)) + ((k) * 2)) ^ (((r) & 7) << 4))

__device__ __forceinline__ unsigned short f2bf(float f) {  // RNE f32->bf16
  unsigned u = __float_as_uint(f);
  u += 0x7FFFu + ((u >> 16) & 1u);
  return (unsigned short)(u >> 16);
}
__device__ __forceinline__ short8 pack8(const float* f) {
  short8 r;
  r[0] = (short)f2bf(f[0]); r[1] = (short)f2bf(f[1]);
  r[2] = (short)f2bf(f[2]); r[3] = (short)f2bf(f[3]);
  r[4] = (short)f2bf(f[4]); r[5] = (short)f2bf(f[5]);
  r[6] = (short)f2bf(f[6]); r[7] = (short)f2bf(f[7]);
  return r;
}

// ---------------------------------------------------------------------------
// Kernel 1: lengths -> out tail (f32). (No barrier flags anymore.)
// ---------------------------------------------------------------------------
__global__ void lengths_init_kernel(const float* __restrict__ emb,
                                    float* __restrict__ out) {
  const int b   = blockIdx.x;
  const int tid = threadIdx.x;
  const int wave = tid >> 6, lane = tid & 63;
  int cnt = 0;
  for (int t = wave; t < TSTEPS; t += 4) {
    const float* row = emb + ((size_t)t * BSZ + b) * INDIM;
    float s = 0.f;
    for (int i = lane; i < INDIM; i += 64) s += row[i];
#pragma unroll
    for (int m = 32; m >= 1; m >>= 1) s += __shfl_xor(s, m, 64);
    if (s != 0.f) ++cnt;
  }
  __shared__ int part[4];
  if (lane == 0) part[wave] = cnt;
  __syncthreads();
  if (tid == 0)
    out[(size_t)BSZ * TSTEPS * DIMR + b] =
        (float)(part[0] + part[1] + part[2] + part[3]);
}

// ---------------------------------------------------------------------------
// Kernel 2: persistent MFMA recurrent kernel, exchange v4 (tag-in-data).
// Grid 256 wgs x 512 thr. Group g (8 wgs, one XCD) owns batches [2g,2g+2).
// wg slice owns 128 rows of W as bf16 B-frags in VGPRs; wave w owns cols
// [slice*128+16w, +16) over the FULL K (32 lw + 10 emb MFMA, no reduce).
// Each output f32 word carries the step tag in its low 16 bits; readers
// poll their own data words (one L3 round trip; no flags, no fences).
// ---------------------------------------------------------------------------
__global__ __launch_bounds__(WGSZ, 2) void esn_recurrent_kernel(
    const float* __restrict__ emb,
    const float* __restrict__ inw,
    const float* __restrict__ lw,
    const float* __restrict__ bias,
    const float* __restrict__ x0,
    float* __restrict__ out) {

  __shared__ __align__(16) unsigned short a_x[16 * 1024];     // 32 KB swizzled
  __shared__ __align__(16) unsigned short aemb[2][16 * EPAD]; // 20 KB swizzled

  const int bid   = blockIdx.x;
  const int xcd   = bid & 7;
  const int ix    = bid >> 3;              // 0..31
  const int group = xcd * 4 + (ix & 3);    // 0..31 (8 wgs of a group on one XCD)
  const int slice = ix >> 2;               // 0..7
  const int tid = threadIdx.x;
  const int w   = tid >> 6, l = tid & 63;
  const int c15 = l & 15, kg = l >> 4;     // B col within tile ; k-group
  const int b0  = group * BPG;
  const int d   = slice * 128 + w * 16 + c15;   // this lane's output dim

  // ---- B-fragments: W row d (bf16), full K
  short8 wB[32];   // layer_w: 32 slices of K=32
  short8 wE[10];   // input_w: 10 slices (K padded 300->320)
#pragma unroll
  for (int s = 0; s < 32; ++s) {
    const int k = s * 32 + kg * 8;
    const float* src = lw + (size_t)d * DIMR + k;
    float tmp[8];
    float4 f0 = *(const float4*)(src);
    float4 f1 = *(const float4*)(src + 4);
    tmp[0] = f0.x; tmp[1] = f0.y; tmp[2] = f0.z; tmp[3] = f0.w;
    tmp[4] = f1.x; tmp[5] = f1.y; tmp[6] = f1.z; tmp[7] = f1.w;
    wB[s] = pack8(tmp);
  }
#pragma unroll
  for (int se = 0; se < 10; ++se) {
    const int ke = se * 32 + kg * 8;
    float tmp[8];
#pragma unroll
    for (int j = 0; j < 8; ++j)
      tmp[j] = (ke + j < INDIM) ? inw[(size_t)d * INDIM + ke + j] : 0.f;
    wE[se] = pack8(tmp);
  }
  const float biasr = bias[d];

  float lenf[BPG];
#pragma unroll
  for (int b = 0; b < BPG; ++b)
    lenf[b] = out[(size_t)BSZ * TSTEPS * DIMR + b0 + b];
  float xo[BPG];                 // exact f32 running state (lanes<16 use it)
#pragma unroll
  for (int r = 0; r < BPG; ++r) xo[r] = x0[d];

  // ---- init LDS: x0 -> a_x rows 0-1, zero rows 2-15, zero aemb
  {
    const short8 z = {0, 0, 0, 0, 0, 0, 0, 0};
    for (int u = 256 + tid; u < 2048; u += WGSZ)   // a_x rows 2-15
      *((short8*)a_x + u) = z;
    for (int u = tid; u < 2 * 16 * EPAD / 8; u += WGSZ)
      *((short8*)&aemb[0][0] + u) = z;
    if (tid < 256) {
      const int r = tid >> 7, k0 = (tid & 127) * 8;
      float tmp[8];
#pragma unroll
      for (int j = 0; j < 8; ++j) tmp[j] = x0[k0 + j];
      *(short8*)((char*)a_x + AX_BYTE(r, k0)) = pack8(tmp);
    }
  }
  __syncthreads();
  if (tid < 150) {  // emb t=0 -> aemb[0] rows 0-1
    const int pb = tid / 75, pq = tid % 75;
    float4 v = *(const float4*)(emb + ((size_t)(b0 + pb)) * INDIM + pq * 4);
    short4v dd;
    dd[0] = (short)f2bf(v.x); dd[1] = (short)f2bf(v.y);
    dd[2] = (short)f2bf(v.z); dd[3] = (short)f2bf(v.w);
    *(short4v*)((char*)&aemb[0][0] + AE_BYTE(pb, pq * 4)) = dd;
  }
  __syncthreads();

  for (int t = 0; t < TSTEPS; ++t) {
    const int cur = t & 1, nxt = cur ^ 1;
    const unsigned tagv = (unsigned)t;

    // emb prefetch for t+1 (global loads early; LDS stash later)
    float4 pf; int pb = 0, pq = 0;
    const bool do_pf = (t + 1 < TSTEPS) && (tid < 150);
    if (do_pf) {
      pb = tid / 75; pq = tid % 75;
      pf = *(const float4*)(emb +
            ((size_t)(t + 1) * BSZ + b0 + pb) * INDIM + pq * 4);
    }

    // ---- MFMA: this wave's 16 cols, full K (4 accumulators, dep-dist 4)
    f32x4 ac[4];
    ac[0] = (f32x4){0.f, 0.f, 0.f, 0.f};
    ac[1] = ac[0]; ac[2] = ac[0]; ac[3] = ac[0];
    const char* axp = (const char*)a_x;
    const char* aep = (const char*)&aemb[cur][0];
#pragma unroll
    for (int s = 0; s < 32; ++s) {
      const int k = s * 32 + kg * 8;
      short8 af = *(const short8*)(axp + AX_BYTE(c15, k));
      ac[s & 3] = __builtin_amdgcn_mfma_f32_16x16x32_bf16(af, wB[s], ac[s & 3], 0, 0, 0);
    }
#pragma unroll
    for (int se = 0; se < 10; ++se) {
      const int ke = se * 32 + kg * 8;
      short8 af = *(const short8*)(aep + AE_BYTE(c15, ke));
      ac[se & 3] = __builtin_amdgcn_mfma_f32_16x16x32_bf16(af, wE[se], ac[se & 3], 0, 0, 0);
    }
    f32x4 cs = (ac[0] + ac[1]) + (ac[2] + ac[3]);

    // ---- finalize (all 8 waves, lanes 0-15; C rows 0-1 = batches) + tagged store
    if (l < 16) {
#pragma unroll
      for (int r = 0; r < BPG; ++r) {
        float u  = cs[r] + biasr;
        float xn = LEAKF * tanhf(u) + (1.f - LEAKF) * xo[r];
        if ((float)t >= lenf[r]) xn = 0.f;
        xo[r] = xn;
        unsigned bits = (__float_as_uint(xn) & 0xFFFF0000u) | tagv;
        __hip_atomic_store(
            (unsigned*)out + ((size_t)(b0 + r) * TSTEPS + t) * DIMR + d,
            bits, __ATOMIC_RELAXED, __HIP_MEMORY_SCOPE_SYSTEM);
      }
    }

    // stash prefetched emb into the other LDS buffer (not read this step)
    if (do_pf) {
      short4v dd;
      dd[0] = (short)f2bf(pf.x); dd[1] = (short)f2bf(pf.y);
      dd[2] = (short)f2bf(pf.z); dd[3] = (short)f2bf(pf.w);
      *(short4v*)((char*)&aemb[nxt][0] + AE_BYTE(pb, pq * 4)) = dd;
    }

    __syncthreads();   // all waves done reading a_x for step t; stores issued

    if (t + 1 < TSTEPS) {
      // ---- poll+reload: each thread owns 4 contiguous words of x_{t+1}
      const int r  = tid >> 8;            // batch row 0/1
      const int k0 = (tid & 255) * 4;     // col
      const unsigned* src =
          (const unsigned*)out + ((size_t)(b0 + r) * TSTEPS + t) * DIMR + k0;
      unsigned v0, v1, v2, v3;
      for (;;) {
        v0 = __hip_atomic_load(src + 0, __ATOMIC_RELAXED, __HIP_MEMORY_SCOPE_SYSTEM);
        v1 = __hip_atomic_load(src + 1, __ATOMIC_RELAXED, __HIP_MEMORY_SCOPE_SYSTEM);
        v2 = __hip_atomic_load(src + 2, __ATOMIC_RELAXED, __HIP_MEMORY_SCOPE_SYSTEM);
        v3 = __hip_atomic_load(src + 3, __ATOMIC_RELAXED, __HIP_MEMORY_SCOPE_SYSTEM);
        unsigned bad = ((v0 ^ tagv) | (v1 ^ tagv) | (v2 ^ tagv) | (v3 ^ tagv)) & 0xFFFFu;
        if (bad == 0) break;
        __builtin_amdgcn_s_sleep(1);
      }
      short4v dd;
      dd[0] = (short)(v0 >> 16); dd[1] = (short)(v1 >> 16);
      dd[2] = (short)(v2 >> 16); dd[3] = (short)(v3 >> 16);
      *(short4v*)((char*)a_x + AX_BYTE(r, k0)) = dd;
      __syncthreads();
    }
  }
}

// ---------------------------------------------------------------------------
extern "C" void kernel_launch(void* const* d_in, const int* in_sizes, int n_in,
                              void* d_out, int out_size, void* d_ws,
                              size_t ws_size, hipStream_t stream) {
  const float* emb  = (const float*)d_in[0];
  const float* inw  = (const float*)d_in[1];
  const float* lw   = (const float*)d_in[2];
  const float* bias = (const float*)d_in[3];
  const float* x0   = (const float*)d_in[4];
  float* out = (float*)d_out;

  hipLaunchKernelGGL(lengths_init_kernel, dim3(BSZ), dim3(256), 0, stream,
                     emb, out);
  hipLaunchKernelGGL(esn_recurrent_kernel, dim3(GROUPS * WPG), dim3(WGSZ), 0,
                     stream, emb, inw, lw, bias, x0, out);
}